// Round 5
// baseline (258.020 us; speedup 1.0000x reference)
//
#include <hip/hip_runtime.h>
#include <math.h>

namespace {
constexpr int V = 2;
constexpr int B = 16384;
constexpr int C = 100;
constexpr int D = 512;
constexpr float MARGIN = 10.0f;
constexpr float EPS = 1e-8f;

constexpr int NB = 2048;            // exactly 8192 waves = device capacity
constexpr int ROWS_PER_WAVE = 4;    // 2048 blocks * 4 waves * 4 rows = 32768
constexpr int IB_PER_V = 8;         // inter chunks per v (handled by blocks 0..15)
constexpr int IB = V * IB_PER_V;    // 16
constexpr int CHUNK = 13;           // ceil(100/8)

// ws float layout: [0,NB) dd-partials | [NB,NB+IB) s-partials
//                  | [NB+IB, NB+IB+IB*D) m-partials | counter (uint) after that
constexpr int WS_DD  = 0;
constexpr int WS_S   = NB;
constexpr int WS_M   = NB + IB;
constexpr int WS_CNT = NB + IB + IB * D;   // float-index of the 4-byte counter
}

__global__ __launch_bounds__(256) void main_kernel(
    const float* __restrict__ feat, const int* __restrict__ label,
    const float* __restrict__ anchor, float* __restrict__ sims,
    float* __restrict__ ws, unsigned* __restrict__ cnt,
    float* __restrict__ out)
{
    __shared__ float blk[4];
    const int wave = threadIdx.x >> 6;
    const int lane = threadIdx.x & 63;

    // ---------- per-row part: 1 wave = 4 consecutive (v,b) rows ----------
    const int wid = blockIdx.x * 4 + wave;               // 0..8191
    float s_dd = 0.f;
#pragma unroll
    for (int r = 0; r < ROWS_PER_WAVE; ++r) {
        const int row = wid * ROWS_PER_WAVE + r;         // row = v*B + b
        const int v = row >> 14;                         // / B
        const int b = row & (B - 1);
        const float* frow = feat + (size_t)row * D;
        const float* crow = anchor + ((size_t)v * C + label[b]) * D;
        float s_ff = 0.f, s_cc = 0.f, s_fc = 0.f;
#pragma unroll
        for (int h = 0; h < 2; ++h) {
            const int d = h * 256 + lane * 4;
            const float4 f = *reinterpret_cast<const float4*>(frow + d);
            const float4 c = *reinterpret_cast<const float4*>(crow + d);
            s_ff += f.x*f.x + f.y*f.y + f.z*f.z + f.w*f.w;
            s_cc += c.x*c.x + c.y*c.y + c.z*c.z + c.w*c.w;
            s_fc += f.x*c.x + f.y*c.y + f.z*c.z + f.w*c.w;
            const float dx = f.x-c.x, dy = f.y-c.y, dz = f.z-c.z, dw = f.w-c.w;
            s_dd += dx*dx + dy*dy + dz*dz + dw*dw;
        }
#pragma unroll
        for (int off = 32; off; off >>= 1) {
            s_ff += __shfl_xor(s_ff, off);
            s_cc += __shfl_xor(s_cc, off);
            s_fc += __shfl_xor(s_fc, off);
        }
        if (lane == 0) {
            const float fn = fmaxf(sqrtf(s_ff), EPS);
            const float cn = fmaxf(sqrtf(s_cc), EPS);
            sims[row] = s_fc / (fn * cn);
        }
    }
#pragma unroll
    for (int off = 32; off; off >>= 1) s_dd += __shfl_xor(s_dd, off);
    if (lane == 0) blk[wave] = s_dd;
    __syncthreads();
    if (threadIdx.x == 0)
        ws[WS_DD + blockIdx.x] = blk[0] + blk[1] + blk[2] + blk[3];

    // ---------- inter part (closed form), folded into blocks 0..15 ----------
    if (blockIdx.x < IB) {
        const int ib = blockIdx.x;
        const int v = ib >> 3, chunk = ib & 7;
        const int c0 = chunk * CHUNK;
        const int c1 = (c0 + CHUNK < C) ? c0 + CHUNK : C;
        const float* a = anchor + (size_t)v * C * D;
        const int d0 = threadIdx.x, d1 = threadIdx.x + 256;
        float m0 = 0.f, m1 = 0.f, s = 0.f;
        for (int c = c0; c < c1; ++c) {
            const float x0 = a[(size_t)c * D + d0];
            const float x1 = a[(size_t)c * D + d1];
            m0 += x0; m1 += x1; s += x0*x0 + x1*x1;
        }
        ws[WS_M + ib * D + d0] = m0;
        ws[WS_M + ib * D + d1] = m1;
#pragma unroll
        for (int off = 32; off; off >>= 1) s += __shfl_xor(s, off);
        __syncthreads();                     // WAR on blk
        if (lane == 0) blk[wave] = s;
        __syncthreads();
        if (threadIdx.x == 0)
            ws[WS_S + ib] = blk[0] + blk[1] + blk[2] + blk[3];
    }

    // ---------- last-block finalize ----------
    __threadfence();                          // release partials (device scope)
    __shared__ unsigned last;
    if (threadIdx.x == 0) last = atomicAdd(cnt, 1u);
    __syncthreads();
    if (last == NB - 1) {
        __threadfence();                      // acquire
        const int t = threadIdx.x;
        float sdd = 0.f;
#pragma unroll
        for (int i = 0; i < 8; ++i) sdd += ws[WS_DD + t + i * 256];
        float mm0 = 0.f, mm1 = 0.f;
#pragma unroll
        for (int h = 0; h < 2; ++h) {
            const int d = t + h * 256;
            float m0 = 0.f, m1 = 0.f;
#pragma unroll
            for (int k = 0; k < IB_PER_V; ++k) {
                m0 += ws[WS_M + (0 * IB_PER_V + k) * D + d];
                m1 += ws[WS_M + (1 * IB_PER_V + k) * D + d];
            }
            mm0 += m0 * m0; mm1 += m1 * m1;
        }
#pragma unroll
        for (int off = 32; off; off >>= 1) {
            sdd += __shfl_xor(sdd, off);
            mm0 += __shfl_xor(mm0, off);
            mm1 += __shfl_xor(mm1, off);
        }
        __shared__ float rr[3][4];
        if (lane == 0) { rr[0][wave] = sdd; rr[1][wave] = mm0; rr[2][wave] = mm1; }
        __syncthreads();
        if (t == 0) {
            const float ddt = rr[0][0] + rr[0][1] + rr[0][2] + rr[0][3];
            const float MM0 = rr[1][0] + rr[1][1] + rr[1][2] + rr[1][3];
            const float MM1 = rr[2][0] + rr[2][1] + rr[2][2] + rr[2][3];
            float S0 = 0.f, S1 = 0.f;
            for (int k = 0; k < IB_PER_V; ++k) {
                S0 += ws[WS_S + k];
                S1 += ws[WS_S + IB_PER_V + k];
            }
            const float denom = (float)(C * (C - 1));
            const float i0 = ((float)C * S0 - MM0) / denom;
            const float i1 = ((float)C * S1 - MM1) / denom;
            const float il = 0.5f * (fmaxf(MARGIN - i0, 0.f) +
                                     fmaxf(MARGIN - i1, 0.f));
            out[0] = ddt / (4.0f * (float)B) + il;   // mean_v(dd_v/(2B)) = ddt/(4B)
        }
    }
}

extern "C" void kernel_launch(void* const* d_in, const int* in_sizes, int n_in,
                              void* d_out, int out_size, void* d_ws, size_t ws_size,
                              hipStream_t stream)
{
    const float* feat   = (const float*)d_in[0];
    const int*   label  = (const int*)d_in[1];
    const float* anchor = (const float*)d_in[2];
    float* out  = (float*)d_out;          // [0] = loss, [1..32768] = sims
    float* ws   = (float*)d_ws;
    float* sims = out + 1;
    unsigned* cnt = (unsigned*)(ws + WS_CNT);

    hipMemsetAsync(cnt, 0, sizeof(unsigned), stream);
    hipLaunchKernelGGL(main_kernel, dim3(NB), dim3(256), 0, stream,
                       feat, label, anchor, sims, ws, cnt, out);
}

// Round 6
// 99.359 us; speedup vs baseline: 2.5968x; 2.5968x over previous
//
#include <hip/hip_runtime.h>
#include <math.h>

namespace {
constexpr int V = 2;
constexpr int B = 16384;
constexpr int C = 100;
constexpr int D = 512;
constexpr float MARGIN = 10.0f;
constexpr float EPS = 1e-8f;

constexpr int NB = 2048;            // exactly 8192 waves = one full device residency
constexpr int ROWS_PER_WAVE = 4;    // 2048 blocks * 4 waves * 4 rows = 32768 rows
constexpr int IB_PER_V = 8;         // inter chunks per v (folded into blocks 0..15)
constexpr int IB = V * IB_PER_V;    // 16
constexpr int CHUNK = 13;           // ceil(100/8)

// ws float layout: [0,NB) dd-partials | [NB,NB+IB) s-partials | [NB+IB, +IB*D) m-partials
constexpr int WS_DD = 0;
constexpr int WS_S  = NB;
constexpr int WS_M  = NB + IB;
}

// Coherence between main_kernel and finalize_kernel comes from the kernel
// boundary on the same stream — NO device-scope fences/atomics (round-5
// lesson: per-block __threadfence() costs ~160us in L2 writebacks).
__global__ __launch_bounds__(256) void main_kernel(
    const float* __restrict__ feat, const int* __restrict__ label,
    const float* __restrict__ anchor, float* __restrict__ sims,
    float* __restrict__ ws)
{
    __shared__ float blk[4];
    const int wave = threadIdx.x >> 6;
    const int lane = threadIdx.x & 63;

    // ---------- per-row part: 1 wave = 4 consecutive (v,b) rows ----------
    const int wid = blockIdx.x * 4 + wave;               // 0..8191
    float s_dd = 0.f;
#pragma unroll
    for (int r = 0; r < ROWS_PER_WAVE; ++r) {
        const int row = wid * ROWS_PER_WAVE + r;         // row = v*B + b
        const int v = row >> 14;                         // / B
        const int b = row & (B - 1);
        const float* frow = feat + (size_t)row * D;
        const float* crow = anchor + ((size_t)v * C + label[b]) * D;
        float s_ff = 0.f, s_cc = 0.f, s_fc = 0.f;
#pragma unroll
        for (int h = 0; h < 2; ++h) {
            const int d = h * 256 + lane * 4;
            const float4 f = *reinterpret_cast<const float4*>(frow + d);
            const float4 c = *reinterpret_cast<const float4*>(crow + d);
            s_ff += f.x*f.x + f.y*f.y + f.z*f.z + f.w*f.w;
            s_cc += c.x*c.x + c.y*c.y + c.z*c.z + c.w*c.w;
            s_fc += f.x*c.x + f.y*c.y + f.z*c.z + f.w*c.w;
            const float dx = f.x-c.x, dy = f.y-c.y, dz = f.z-c.z, dw = f.w-c.w;
            s_dd += dx*dx + dy*dy + dz*dz + dw*dw;
        }
#pragma unroll
        for (int off = 32; off; off >>= 1) {
            s_ff += __shfl_xor(s_ff, off);
            s_cc += __shfl_xor(s_cc, off);
            s_fc += __shfl_xor(s_fc, off);
        }
        if (lane == 0) {
            const float fn = fmaxf(sqrtf(s_ff), EPS);
            const float cn = fmaxf(sqrtf(s_cc), EPS);
            sims[row] = s_fc / (fn * cn);
        }
    }
#pragma unroll
    for (int off = 32; off; off >>= 1) s_dd += __shfl_xor(s_dd, off);
    if (lane == 0) blk[wave] = s_dd;
    __syncthreads();
    if (threadIdx.x == 0)
        ws[WS_DD + blockIdx.x] = blk[0] + blk[1] + blk[2] + blk[3];

    // ---------- inter part (closed form), folded into blocks 0..15 ----------
    // inter = (C*S - ||m||^2)/(C*(C-1)) with S = sum a^2, m = column-sum.
    if (blockIdx.x < IB) {
        const int ib = blockIdx.x;
        const int v = ib >> 3, chunk = ib & 7;
        const int c0 = chunk * CHUNK;
        const int c1 = (c0 + CHUNK < C) ? c0 + CHUNK : C;
        const float* a = anchor + (size_t)v * C * D;
        const int d0 = threadIdx.x, d1 = threadIdx.x + 256;
        float m0 = 0.f, m1 = 0.f, s = 0.f;
        for (int c = c0; c < c1; ++c) {
            const float x0 = a[(size_t)c * D + d0];
            const float x1 = a[(size_t)c * D + d1];
            m0 += x0; m1 += x1; s += x0*x0 + x1*x1;
        }
        ws[WS_M + ib * D + d0] = m0;
        ws[WS_M + ib * D + d1] = m1;
#pragma unroll
        for (int off = 32; off; off >>= 1) s += __shfl_xor(s, off);
        __syncthreads();                     // WAR on blk
        if (lane == 0) blk[wave] = s;
        __syncthreads();
        if (threadIdx.x == 0)
            ws[WS_S + ib] = blk[0] + blk[1] + blk[2] + blk[3];
    }
}

// Single block: reduce dd-partials, chunked m-vectors, s-partials; emit loss.
__global__ __launch_bounds__(1024) void finalize_kernel(
    const float* __restrict__ ws, float* __restrict__ out)
{
    const int t = threadIdx.x;
    const int wave = t >> 6, lane = t & 63;

    float sdd = ws[WS_DD + t] + ws[WS_DD + t + 1024];

    const int v = t >> 9, d = t & 511;     // waves 0-7 -> v=0, 8-15 -> v=1
    float m = 0.f;
#pragma unroll
    for (int k = 0; k < IB_PER_V; ++k)
        m += ws[WS_M + ((size_t)v * IB_PER_V + k) * D + d];
    float mm = m * m;

#pragma unroll
    for (int off = 32; off; off >>= 1) {
        sdd += __shfl_xor(sdd, off);
        mm  += __shfl_xor(mm, off);
    }
    __shared__ float rdd[16], rmm[16];
    if (lane == 0) { rdd[wave] = sdd; rmm[wave] = mm; }
    __syncthreads();
    if (t == 0) {
        float ddt = 0.f;
        for (int w = 0; w < 16; ++w) ddt += rdd[w];
        float MM0 = 0.f, MM1 = 0.f;
        for (int w = 0; w < 8;  ++w) MM0 += rmm[w];
        for (int w = 8; w < 16; ++w) MM1 += rmm[w];
        float S0 = 0.f, S1 = 0.f;
        for (int k = 0; k < IB_PER_V; ++k) {
            S0 += ws[WS_S + k];
            S1 += ws[WS_S + IB_PER_V + k];
        }
        const float denom = (float)(C * (C - 1));
        const float i0 = ((float)C * S0 - MM0) / denom;
        const float i1 = ((float)C * S1 - MM1) / denom;
        const float il = 0.5f * (fmaxf(MARGIN - i0, 0.f) +
                                 fmaxf(MARGIN - i1, 0.f));
        out[0] = ddt / (4.0f * (float)B) + il;   // mean_v(dd_v/(2B)) = ddt/(4B)
    }
}

extern "C" void kernel_launch(void* const* d_in, const int* in_sizes, int n_in,
                              void* d_out, int out_size, void* d_ws, size_t ws_size,
                              hipStream_t stream)
{
    const float* feat   = (const float*)d_in[0];
    const int*   label  = (const int*)d_in[1];
    const float* anchor = (const float*)d_in[2];
    float* out  = (float*)d_out;          // [0] = loss, [1..32768] = sims
    float* ws   = (float*)d_ws;
    float* sims = out + 1;

    hipLaunchKernelGGL(main_kernel, dim3(NB), dim3(256), 0, stream,
                       feat, label, anchor, sims, ws);
    hipLaunchKernelGGL(finalize_kernel, dim3(1), dim3(1024), 0, stream,
                       ws, out);
}